// Round 1
// 628.151 us; speedup vs baseline: 1.3828x; 1.3828x over previous
//
#include <hip/hip_runtime.h>
#include <hip/hip_bf16.h>

// CrissCrossAttentionBlock: B=8, H=W=96, C=512, c=64. N = 73728 pixels.
// External tensors fp32. Internals: xb,q,k,v,yv,Av,Ah bf16; S fp32.
//
// Pipeline:
//  0) conv_x: x fp32 -> xb bf16 (row-major); conv_w x3: W fp32 -> fragment-major bf16
//  1) mfma_proj x3: q,k (Nx64 bf16), v (Nx512 bf16) via 16x16x32 bf16 MFMA
//  2) cc_scores (MFMA, no LDS): S[n][0:96] vertical (diag -1e30), [96:192] horizontal
//  3) cc_softmax: per-pixel softmax over 192 logits; writes bf16 probs Av/Ah
//     INTO the S rows (Av at byte 0..191, Ah at byte 192..383 of each 768B row)
//  4) cc_aggr_v (MFMA): yv = Av @ V  (V-tile staged in LDS, u16 B-frag gather)
//  5) cc_aggr_h_final (MFMA): out = (yv + Ah@V)*gamma + x (fp32)

#define NPIX 73728
#define HH 96
#define WW 96
#define CC 512
#define CQ 64
#define PA 384   // short-pitch of A rows embedded in S rows (768 B)

typedef __attribute__((ext_vector_type(8))) short bf16x8;
typedef __attribute__((ext_vector_type(4))) float f32x4;

__device__ __forceinline__ void async16(const void* g, void* l) {
    __builtin_amdgcn_global_load_lds(
        (const __attribute__((address_space(1))) unsigned int*)g,
        (__attribute__((address_space(3))) unsigned int*)l,
        16, 0, 0);
}

// ---------------------------------------------------------------------------
// 0a) x fp32 -> bf16, row-major. 8 elems per thread.
// ---------------------------------------------------------------------------
__global__ __launch_bounds__(256) void conv_x(
    const float* __restrict__ x, short* __restrict__ xb)
{
    size_t i8 = ((size_t)blockIdx.x * 256 + threadIdx.x) * 8;
    float4 a = *reinterpret_cast<const float4*>(x + i8);
    float4 b = *reinterpret_cast<const float4*>(x + i8 + 4);
    union { __hip_bfloat16 h[8]; uint4 u; } pk;
    pk.h[0] = __float2bfloat16(a.x); pk.h[1] = __float2bfloat16(a.y);
    pk.h[2] = __float2bfloat16(a.z); pk.h[3] = __float2bfloat16(a.w);
    pk.h[4] = __float2bfloat16(b.x); pk.h[5] = __float2bfloat16(b.y);
    pk.h[6] = __float2bfloat16(b.z); pk.h[7] = __float2bfloat16(b.w);
    *reinterpret_cast<uint4*>(xb + i8) = pk.u;
}

// ---------------------------------------------------------------------------
// 0b) W (512 x J fp32, row-major) -> B-fragment-major bf16:
//     dst[((kb32*(J/16)+ntile)*64 + lane)*8 + j] =
//        W[kb32*32 + (lane>>4)*8 + j][ntile*16 + (lane&15)]
// ---------------------------------------------------------------------------
__global__ __launch_bounds__(256) void conv_w(
    const float* __restrict__ W, short* __restrict__ dst, int J)
{
    int idx = blockIdx.x * 256 + threadIdx.x;   // one 8-elem fragment per thread
    int lane = idx & 63;
    int blk = idx >> 6;
    int ntiles = J >> 4;
    int ntile = blk % ntiles;
    int kb32 = blk / ntiles;
    int krow = kb32 * 32 + (lane >> 4) * 8;
    int col = ntile * 16 + (lane & 15);
    union { __hip_bfloat16 h[8]; uint4 u; } pk;
    #pragma unroll
    for (int j = 0; j < 8; ++j)
        pk.h[j] = __float2bfloat16(W[(size_t)(krow + j) * J + col]);
    *reinterpret_cast<uint4*>(dst + (size_t)idx * 8) = pk.u;
}

// ---------------------------------------------------------------------------
// 1) MFMA projection GEMM: out[n][j] = xb[n][:] @ W[:][j] + bias[j]
// ---------------------------------------------------------------------------
template <int BN>
__global__ __launch_bounds__(256) void mfma_proj(
    const short* __restrict__ Xb,    // N x 512 bf16
    const short* __restrict__ Wf,    // fragment-major bf16
    const float* __restrict__ bias,  // J fp32
    short* __restrict__ out,         // N x J bf16
    int J)
{
    __shared__ __align__(16) short Albuf[128 * 32];   // fragment-major, 8 KB
    const int tid = threadIdx.x;
    const int lane = tid & 63;
    const int w = tid >> 6;
    const int mBase = blockIdx.x * 128;
    const int nBase = blockIdx.y * BN;

    constexpr int MT = (BN == 128) ? 4 : 2;
    constexpr int NT = 4;
    const int wr = (BN == 128) ? (w >> 1) : w;
    const int wc = (BN == 128) ? (w & 1) : 0;
    const int tbase = wr * MT;
    const int nTile0 = (nBase >> 4) + wc * 4;
    const int ntilesJ = J >> 4;

    f32x4 acc[MT][NT];
    #pragma unroll
    for (int i = 0; i < MT; ++i)
        #pragma unroll
        for (int j = 0; j < NT; ++j) {
            f32x4 z = {0.f, 0.f, 0.f, 0.f};
            acc[i][j] = z;
        }

    const int arow0 = lane & 15;        // m within tile
    const int acol0 = (lane >> 4) * 8;  // k within 32

    for (int kb = 0; kb < 16; ++kb) {
        #pragma unroll
        for (int s = 0; s < 2; ++s) {
            int t = w * 2 + s;
            const short* g = Xb + (size_t)(mBase + t * 16 + arow0) * 512 + kb * 32 + acol0;
            async16(g, &Albuf[t * 512]);
        }
        __syncthreads();

        bf16x8 bf[NT];
        #pragma unroll
        for (int jn = 0; jn < NT; ++jn)
            bf[jn] = *reinterpret_cast<const bf16x8*>(
                Wf + ((size_t)(kb * ntilesJ + nTile0 + jn) * 64 + lane) * 8);
        bf16x8 af[MT];
        #pragma unroll
        for (int i = 0; i < MT; ++i)
            af[i] = *reinterpret_cast<const bf16x8*>(&Albuf[(tbase + i) * 512 + lane * 8]);
        #pragma unroll
        for (int i = 0; i < MT; ++i)
            #pragma unroll
            for (int jn = 0; jn < NT; ++jn)
                acc[i][jn] = __builtin_amdgcn_mfma_f32_16x16x32_bf16(
                    af[i], bf[jn], acc[i][jn], 0, 0, 0);
        __syncthreads();
    }

    // Epilogue: D[row=(lane>>4)*4+r][col=lane&15] per 16x16 tile.
    const int lrow = (lane >> 4) * 4, lcol = lane & 15;
    #pragma unroll
    for (int jn = 0; jn < NT; ++jn) {
        int col = nBase + wc * 64 + jn * 16 + lcol;
        float bc = bias[col];
        #pragma unroll
        for (int i = 0; i < MT; ++i) {
            int row = mBase + wr * (MT * 16) + i * 16 + lrow;
            #pragma unroll
            for (int r = 0; r < 4; ++r) {
                __hip_bfloat16 hb = __float2bfloat16(acc[i][jn][r] + bc);
                out[(size_t)(row + r) * J + col] = *reinterpret_cast<short*>(&hb);
            }
        }
    }
}

// ---------------------------------------------------------------------------
// 2) Scores via MFMA, no LDS. blockIdx.y==0: vertical, ==1: horizontal.
//    Per block: 96x96 output tile, K=64. 4 waves 2x2, wave tile 48x48.
//    A-frag = Q rows, B-frag = K rows (K-dim = channel, contiguous in both).
// ---------------------------------------------------------------------------
__global__ __launch_bounds__(256) void cc_scores(
    const short* __restrict__ Q,   // N x 64 bf16
    const short* __restrict__ K,   // N x 64 bf16
    float* __restrict__ S)         // N x 192 fp32
{
    const int tid = threadIdx.x;
    const int lane = tid & 63;
    const int wv = tid >> 6;
    const int wr = wv >> 1, wc = wv & 1;
    const bool vert = (blockIdx.y == 0);
    const int b = blockIdx.x / 96;
    const int line = blockIdx.x % 96;

    size_t base;
    int rowStride;
    if (vert) { base = (size_t)b * 9216 + line;       rowStride = 96; }
    else      { base = ((size_t)b * 96 + line) * 96;  rowStride = 1;  }

    const int cl = lane & 15;
    const int q8 = (lane >> 4) * 8;

    f32x4 acc[3][3];
    #pragma unroll
    for (int i = 0; i < 3; ++i)
        #pragma unroll
        for (int j = 0; j < 3; ++j) {
            f32x4 z = {0.f, 0.f, 0.f, 0.f};
            acc[i][j] = z;
        }

    #pragma unroll
    for (int kb = 0; kb < 2; ++kb) {
        bf16x8 af[3], bf[3];
        #pragma unroll
        for (int mt = 0; mt < 3; ++mt) {
            size_t n = base + (size_t)(wr * 48 + mt * 16 + cl) * rowStride;
            af[mt] = *reinterpret_cast<const bf16x8*>(Q + n * 64 + kb * 32 + q8);
        }
        #pragma unroll
        for (int nt = 0; nt < 3; ++nt) {
            size_t n = base + (size_t)(wc * 48 + nt * 16 + cl) * rowStride;
            bf[nt] = *reinterpret_cast<const bf16x8*>(K + n * 64 + kb * 32 + q8);
        }
        #pragma unroll
        for (int mt = 0; mt < 3; ++mt)
            #pragma unroll
            for (int nt = 0; nt < 3; ++nt)
                acc[mt][nt] = __builtin_amdgcn_mfma_f32_16x16x32_bf16(
                    af[mt], bf[nt], acc[mt][nt], 0, 0, 0);
    }

    const int lrow = (lane >> 4) * 4;
    const int dirOff = vert ? 0 : 96;
    #pragma unroll
    for (int mt = 0; mt < 3; ++mt) {
        #pragma unroll
        for (int r = 0; r < 4; ++r) {
            int i = wr * 48 + mt * 16 + lrow + r;
            size_t n = base + (size_t)i * rowStride;
            float* srow = S + n * 192 + dirOff;
            #pragma unroll
            for (int nt = 0; nt < 3; ++nt) {
                int j = wc * 48 + nt * 16 + cl;
                srow[j] = (vert && i == j) ? -1e30f : acc[mt][nt][r];
            }
        }
    }
}

// ---------------------------------------------------------------------------
// 3) Softmax over 192 logits per pixel. One wave per pixel.
//    Writes bf16 probabilities INTO the row: Av = shorts [0,96), Ah = [96,192).
//    Safe: all loads of the row feed the cross-lane reductions, so every
//    lane's stores depend on every lane's loads (no read-after-overwrite).
// ---------------------------------------------------------------------------
__global__ __launch_bounds__(256) void cc_softmax(float* __restrict__ S)
{
    const int tid = threadIdx.x;
    const int lane = tid & 63;
    const size_t n = (size_t)blockIdx.x * 4 + (tid >> 6);
    float* row = S + n * 192;
    float s0 = row[lane], s1 = row[lane + 64], s2 = row[lane + 128];
    float m = fmaxf(s0, fmaxf(s1, s2));
    #pragma unroll
    for (int off = 32; off >= 1; off >>= 1) m = fmaxf(m, __shfl_xor(m, off, 64));
    float e0 = expf(s0 - m), e1 = expf(s1 - m), e2 = expf(s2 - m);
    float sum = e0 + e1 + e2;
    #pragma unroll
    for (int off = 32; off >= 1; off >>= 1) sum += __shfl_xor(sum, off, 64);
    float inv = 1.0f / sum;
    __hip_bfloat16 p0 = __float2bfloat16(e0 * inv);
    __hip_bfloat16 p1 = __float2bfloat16(e1 * inv);
    __hip_bfloat16 p2 = __float2bfloat16(e2 * inv);
    short* av = reinterpret_cast<short*>(row);   // 96 shorts (cols 0..95  = Av)
    short* ah = av + 96;                         // 96 shorts (cols 96..191 = Ah)
    av[lane] = *reinterpret_cast<short*>(&p0);
    if (lane < 32) av[64 + lane] = *reinterpret_cast<short*>(&p1);
    else           ah[lane - 32] = *reinterpret_cast<short*>(&p1);
    ah[32 + lane] = *reinterpret_cast<short*>(&p2);
}

// ---------------------------------------------------------------------------
// 4) Vertical aggregation via MFMA: per (b,w) column x 128-c slab:
//    Yv[h][c] = sum_g Av[h][g] * V[(b,g,w)][c].  M=96, N=128, K=96.
//    V-tile staged row-major [g][128] in LDS (async16, contiguous chunks);
//    B-frags gathered as 8 x u16 reads (K-dim is pixel-strided in memory).
// ---------------------------------------------------------------------------
__global__ __launch_bounds__(256) void cc_aggr_v(
    const short* __restrict__ A,     // (short*)S: Av at n*PA
    const short* __restrict__ V,     // N x 512 bf16
    short* __restrict__ Yv)          // N x 512 bf16
{
    __shared__ __align__(16) short Vs[96 * 128];   // 24 KB
    const int tid = threadIdx.x;
    const int lane = tid & 63;
    const int wv = tid >> 6;
    const int b = blockIdx.x / 96;
    const int w = blockIdx.x % 96;
    const int cBase = blockIdx.y * 128;
    const size_t colBase = (size_t)b * 9216 + w;   // pixel n = colBase + g*96

    #pragma unroll
    for (int s = 0; s < 6; ++s) {
        int c0 = (s * 4 + wv) * 64;          // wave-uniform chunk base
        int chunk = c0 + lane;
        int g = chunk >> 4;
        int cc = (chunk & 15) * 8;
        async16(V + (colBase + (size_t)g * 96) * 512 + cBase + cc,
                &Vs[(size_t)c0 * 8]);
    }
    __syncthreads();

    const int wr = wv >> 1, wc = wv & 1;     // wave tile 48 x 64
    const int cl = lane & 15, q = lane >> 4;

    f32x4 acc[3][4];
    #pragma unroll
    for (int i = 0; i < 3; ++i)
        #pragma unroll
        for (int j = 0; j < 4; ++j) {
            f32x4 z = {0.f, 0.f, 0.f, 0.f};
            acc[i][j] = z;
        }

    for (int kb = 0; kb < 3; ++kb) {
        bf16x8 af[3];
        #pragma unroll
        for (int mt = 0; mt < 3; ++mt) {
            size_t n = colBase + (size_t)(wr * 48 + mt * 16 + cl) * 96;
            af[mt] = *reinterpret_cast<const bf16x8*>(A + n * PA + kb * 32 + q * 8);
        }
        #pragma unroll
        for (int nt = 0; nt < 4; ++nt) {
            int col = wc * 64 + nt * 16 + cl;
            bf16x8 bv;
            #pragma unroll
            for (int j = 0; j < 8; ++j)
                bv[j] = Vs[(kb * 32 + q * 8 + j) * 128 + col];
            #pragma unroll
            for (int mt = 0; mt < 3; ++mt)
                acc[mt][nt] = __builtin_amdgcn_mfma_f32_16x16x32_bf16(
                    af[mt], bv, acc[mt][nt], 0, 0, 0);
        }
    }

    const int lrow = q * 4;
    #pragma unroll
    for (int mt = 0; mt < 3; ++mt) {
        #pragma unroll
        for (int r = 0; r < 4; ++r) {
            size_t n = colBase + (size_t)(wr * 48 + mt * 16 + lrow + r) * 96;
            #pragma unroll
            for (int nt = 0; nt < 4; ++nt) {
                int c = cBase + wc * 64 + nt * 16 + cl;
                __hip_bfloat16 hb = __float2bfloat16(acc[mt][nt][r]);
                Yv[n * 512 + c] = *reinterpret_cast<short*>(&hb);
            }
        }
    }
}

// ---------------------------------------------------------------------------
// 5) Horizontal aggregation via MFMA + epilogue: out = (Yv + Ah@V)*gamma + x
// ---------------------------------------------------------------------------
__global__ __launch_bounds__(256) void cc_aggr_h_final(
    const short* __restrict__ A,             // (short*)S: Ah at n*PA + 96
    const short* __restrict__ V,             // N x 512 bf16
    const __hip_bfloat16* __restrict__ Yv,   // N x 512 bf16
    const float* __restrict__ X,             // N x 512 fp32
    const float* __restrict__ gamma_p,
    float* __restrict__ out)                 // N x 512 fp32
{
    __shared__ __align__(16) short Vs[96 * 128];   // 24 KB
    const int tid = threadIdx.x;
    const int lane = tid & 63;
    const int wv = tid >> 6;
    const int b = blockIdx.x / 96;
    const int h = blockIdx.x % 96;
    const int cBase = blockIdx.y * 128;
    const size_t rowBase = (size_t)(b * 96 + h) * 96;   // pixel n = rowBase + u

    #pragma unroll
    for (int s = 0; s < 6; ++s) {
        int c0 = (s * 4 + wv) * 64;
        int chunk = c0 + lane;
        int u = chunk >> 4;
        int cc = (chunk & 15) * 8;
        async16(V + (rowBase + u) * 512 + cBase + cc,
                &Vs[(size_t)c0 * 8]);
    }
    __syncthreads();

    const int wr = wv >> 1, wc = wv & 1;
    const int cl = lane & 15, q = lane >> 4;

    f32x4 acc[3][4];
    #pragma unroll
    for (int i = 0; i < 3; ++i)
        #pragma unroll
        for (int j = 0; j < 4; ++j) {
            f32x4 z = {0.f, 0.f, 0.f, 0.f};
            acc[i][j] = z;
        }

    for (int kb = 0; kb < 3; ++kb) {
        bf16x8 af[3];
        #pragma unroll
        for (int mt = 0; mt < 3; ++mt) {
            size_t n = rowBase + (size_t)(wr * 48 + mt * 16 + cl);
            af[mt] = *reinterpret_cast<const bf16x8*>(A + n * PA + 96 + kb * 32 + q * 8);
        }
        #pragma unroll
        for (int nt = 0; nt < 4; ++nt) {
            int col = wc * 64 + nt * 16 + cl;
            bf16x8 bv;
            #pragma unroll
            for (int j = 0; j < 8; ++j)
                bv[j] = Vs[(kb * 32 + q * 8 + j) * 128 + col];
            #pragma unroll
            for (int mt = 0; mt < 3; ++mt)
                acc[mt][nt] = __builtin_amdgcn_mfma_f32_16x16x32_bf16(
                    af[mt], bv, acc[mt][nt], 0, 0, 0);
        }
    }

    const float gm = gamma_p[0];
    const int lrow = q * 4;
    #pragma unroll
    for (int mt = 0; mt < 3; ++mt) {
        #pragma unroll
        for (int r = 0; r < 4; ++r) {
            size_t n = rowBase + (size_t)(wr * 48 + mt * 16 + lrow + r);
            size_t rowOff = n * 512;
            #pragma unroll
            for (int nt = 0; nt < 4; ++nt) {
                int c = cBase + wc * 64 + nt * 16 + cl;
                size_t off = rowOff + c;
                out[off] = (acc[mt][nt][r] + __bfloat162float(Yv[off])) * gm + X[off];
            }
        }
    }
}

// ---------------------------------------------------------------------------
extern "C" void kernel_launch(void* const* d_in, const int* in_sizes, int n_in,
                              void* d_out, int out_size, void* d_ws, size_t ws_size,
                              hipStream_t stream) {
    const float* x     = (const float*)d_in[0];
    const float* Wq    = (const float*)d_in[1];
    const float* bq    = (const float*)d_in[2];
    const float* Wk    = (const float*)d_in[3];
    const float* bk    = (const float*)d_in[4];
    const float* Wv    = (const float*)d_in[5];
    const float* bv    = (const float*)d_in[6];
    const float* gamma = (const float*)d_in[7];
    float* out = (float*)d_out;

    // Workspace (shorts unless noted); yv aliases xb (dead after projections).
    //   xb  : NPIX*512            = 37,748,736
    //   Wqf : 512*64              =     32,768
    //   Wkf : 512*64              =     32,768
    //   Wvf : 512*512             =    262,144
    //   q,k : NPIX*64 each        =  4,718,592 x2
    //   v   : NPIX*512            = 37,748,736
    //   S   : NPIX*192 fp32       (after v; also hosts bf16 Av/Ah)  total ~217 MiB
    short* xb  = (short*)d_ws;
    short* Wqf = xb + (size_t)NPIX * 512;
    short* Wkf = Wqf + 512 * 64;
    short* Wvf = Wkf + 512 * 64;
    short* q   = Wvf + 512 * 512;
    short* k   = q + (size_t)NPIX * CQ;
    short* v   = k + (size_t)NPIX * CQ;
    float* S   = (float*)(v + (size_t)NPIX * CC);
    __hip_bfloat16* yv = (__hip_bfloat16*)xb;   // alias

    conv_x<<<NPIX * 512 / 8 / 256, 256, 0, stream>>>(x, xb);
    conv_w<<<16, 256, 0, stream>>>(Wq, Wqf, 64);
    conv_w<<<16, 256, 0, stream>>>(Wk, Wkf, 64);
    conv_w<<<128, 256, 0, stream>>>(Wv, Wvf, 512);

    mfma_proj<64><<<dim3(NPIX / 128, 1), 256, 0, stream>>>(xb, Wqf, bq, q, CQ);
    mfma_proj<64><<<dim3(NPIX / 128, 1), 256, 0, stream>>>(xb, Wkf, bk, k, CQ);
    mfma_proj<128><<<dim3(NPIX / 128, 4), 256, 0, stream>>>(xb, Wvf, bv, v, CC);

    cc_scores<<<dim3(8 * 96, 2), 256, 0, stream>>>(q, k, S);
    cc_softmax<<<NPIX / 4, 256, 0, stream>>>(S);

    cc_aggr_v<<<dim3(8 * 96, 4), 256, 0, stream>>>((const short*)S, v, (short*)yv);
    cc_aggr_h_final<<<dim3(8 * 96, 4), 256, 0, stream>>>(
        (const short*)S, v, yv, x, gamma, out);
}